// Round 15
// baseline (355.911 us; speedup 1.0000x reference)
//
#include <hip/hip_runtime.h>
#include <hip/hip_bf16.h>

// FlowNetC correlation via bf16 MFMA Gram (16 tiles/parity, trivial epilogue).
// out[b, dyi*21+j, y, x] = (1/256) * sum_c in1[b,c,y,x] * in2[b,c,y2,x+2j-20], y2=y+2dyi-20.
// Parity split: x=2x'+p, u=2u'+p, u'=x'+j-10. Per (b,y,dyi,p):
//   G_p[x'][u'] = sum_c A_p[x'][c]*B_p[u'][c]  (64x64, K=256); j=u'-x'+10 in [0,21).
// Round-13 fix: raw s_barrier + lgkmcnt(0) instead of __syncthreads(). __syncthreads
// emits s_waitcnt vmcnt(0) before s_barrier -> every barrier drained the in-flight
// prefetch (16 barriers x full L2/L3 latency = the stall; r9/r10/r12 all ~398us
// regardless of staging schedule proved the drain, not pack placement, was binding).

typedef __attribute__((ext_vector_type(8))) short bf16x8;
typedef __attribute__((ext_vector_type(4))) float f32x4;
typedef __attribute__((ext_vector_type(4))) unsigned u32x4;

constexpr int Bn = 8, Cn = 256, Hn = 96, Wn = 128, GW = 21;
constexpr int KC = 32, NCH = Cn / KC;     // 8 chunks of 32 channels
constexpr int NWG = Bn * Hn * GW;         // 16128, divisible by 8
constexpr int CPX = NWG / 8;

__device__ inline unsigned pack_bf16(float lo, float hi) {
    __hip_bfloat16 l = __float2bfloat16(lo);
    __hip_bfloat16 h = __float2bfloat16(hi);
    unsigned short lu, hu;
    __builtin_memcpy(&lu, &l, 2);
    __builtin_memcpy(&hu, &h, 2);
    return (unsigned)lu | ((unsigned)hu << 16);
}

// LDS-visibility barrier WITHOUT the vmcnt(0) drain of __syncthreads():
// drain own ds ops (lgkmcnt covers ds_read+ds_write) -> barrier -> pin (rule #18).
__device__ inline void lds_barrier() {
    asm volatile("s_waitcnt lgkmcnt(0)" ::: "memory");
    __builtin_amdgcn_s_barrier();
    __builtin_amdgcn_sched_barrier(0);
}

__global__ __launch_bounds__(256) void corr_mfma(
    const float* __restrict__ in1, const float* __restrict__ in2,
    float* __restrict__ out)
{
    // [dbuf][panel: Ae,Ao,Be,Bo][1024 uints]; panel = [mt4][kg4][pos16][ku4] of bf16x2
    __shared__ unsigned lds[2][4][1024];

    int orig = blockIdx.x;
    int wg  = (orig & 7) * CPX + (orig >> 3);   // bijective XCD chunking
    int dyi = wg % GW;
    int y   = (wg / GW) % Hn;
    int b   = wg / (GW * Hn);
    int y2  = y + 2 * dyi - 20;
    bool y2ok = (y2 >= 0) && (y2 < Hn);

    int tid = threadIdx.x;
    int w   = tid >> 6;          // wave 0..3
    int l   = tid & 63;
    int p   = w >> 1;            // parity
    int h   = w & 1;             // x-half: mt in {2h, 2h+1}
    int g   = l >> 4;            // k-group
    int m16 = l & 15;

    const size_t chw = (size_t)Hn * Wn;
    const float* pA = in1 + ((size_t)b * Cn) * chw + (size_t)y * Wn;
    const float* pB = in2 + ((size_t)b * Cn) * chw + (size_t)(y2ok ? y2 : 0) * Wn;

    // staging task: thread = (tm = x-pair 0..63, tg = kg 0..3); owns channels 8tg..8tg+7
    int tm = tid & 63;
    int tg = tid >> 6;
    const int loff = ((tm >> 4) * 4 + tg) * 64 + (tm & 15) * 4;   // b128-aligned

    f32x4 acc[2][4] = {};        // acc[a][n] = tile (mt=2h+a, nt=n)

    // raw load values as scalar floats (two prefetch sets)
    float ax0[8], ay0[8], bx0[8], by0[8];
    float ax1[8], ay1[8], bx1[8], by1[8];

    auto prefetch = [&](int chunk, float (&ax)[8], float (&ay)[8],
                        float (&bx)[8], float (&by)[8]) {
        size_t base = (size_t)(chunk * KC + 8 * tg) * chw + 2 * tm;
#pragma unroll
        for (int k = 0; k < 8; ++k) {
            float2 tA = *(const float2*)(pA + base + (size_t)k * chw);
            float2 tB = *(const float2*)(pB + base + (size_t)k * chw);
            ax[k] = tA.x; ay[k] = tA.y;
            bx[k] = tB.x; by[k] = tB.y;
        }
        __builtin_amdgcn_sched_barrier(0);   // pin issue point: loads go out here
    };

    auto writeout = [&](int buf, float (&ax)[8], float (&ay)[8],
                        float (&bx)[8], float (&by)[8]) {
        // keep-alive: packs (and the counted vmcnt wait) stay HERE, not at load site
#pragma unroll
        for (int k = 0; k < 8; ++k)
            asm volatile("" : "+v"(ax[k]), "+v"(ay[k]), "+v"(bx[k]), "+v"(by[k]));
        u32x4 ae, ao, be, bo;
#pragma unroll
        for (int ku = 0; ku < 4; ++ku) {
            ae[ku] = pack_bf16(ax[2 * ku], ax[2 * ku + 1]);
            ao[ku] = pack_bf16(ay[2 * ku], ay[2 * ku + 1]);
            be[ku] = pack_bf16(bx[2 * ku], bx[2 * ku + 1]);
            bo[ku] = pack_bf16(by[2 * ku], by[2 * ku + 1]);
        }
        *(u32x4*)&lds[buf][0][loff] = ae;
        *(u32x4*)&lds[buf][1][loff] = ao;
        *(u32x4*)&lds[buf][2][loff] = be;
        *(u32x4*)&lds[buf][3][loff] = bo;
    };

    auto compute = [&](int buf) {
        const unsigned* Pa = &lds[buf][p][0];
        const unsigned* Pb = &lds[buf][2 + p][0];
        int fo = g * 64 + m16 * 4;
        bf16x8 A0  = *(const bf16x8*)(Pa + (2 * h + 0) * 256 + fo);
        bf16x8 A1  = *(const bf16x8*)(Pa + (2 * h + 1) * 256 + fo);
        bf16x8 Bf0 = *(const bf16x8*)(Pb + 0 * 256 + fo);
        bf16x8 Bf1 = *(const bf16x8*)(Pb + 1 * 256 + fo);
        bf16x8 Bf2 = *(const bf16x8*)(Pb + 2 * 256 + fo);
        bf16x8 Bf3 = *(const bf16x8*)(Pb + 3 * 256 + fo);
        acc[0][0] = __builtin_amdgcn_mfma_f32_16x16x32_bf16(A0, Bf0, acc[0][0], 0, 0, 0);
        acc[0][1] = __builtin_amdgcn_mfma_f32_16x16x32_bf16(A0, Bf1, acc[0][1], 0, 0, 0);
        acc[0][2] = __builtin_amdgcn_mfma_f32_16x16x32_bf16(A0, Bf2, acc[0][2], 0, 0, 0);
        acc[0][3] = __builtin_amdgcn_mfma_f32_16x16x32_bf16(A0, Bf3, acc[0][3], 0, 0, 0);
        acc[1][0] = __builtin_amdgcn_mfma_f32_16x16x32_bf16(A1, Bf0, acc[1][0], 0, 0, 0);
        acc[1][1] = __builtin_amdgcn_mfma_f32_16x16x32_bf16(A1, Bf1, acc[1][1], 0, 0, 0);
        acc[1][2] = __builtin_amdgcn_mfma_f32_16x16x32_bf16(A1, Bf2, acc[1][2], 0, 0, 0);
        acc[1][3] = __builtin_amdgcn_mfma_f32_16x16x32_bf16(A1, Bf3, acc[1][3], 0, 0, 0);
    };

    if (y2ok) {
        prefetch(0, ax0, ay0, bx0, by0);
        prefetch(1, ax1, ay1, bx1, by1);
        for (int it = 0; it < NCH; it += 2) {
            writeout(0, ax0, ay0, bx0, by0);
            lds_barrier();
            if (it + 2 < NCH) prefetch(it + 2, ax0, ay0, bx0, by0);
            compute(0);
            writeout(1, ax1, ay1, bx1, by1);
            lds_barrier();
            if (it + 3 < NCH) prefetch(it + 3, ax1, ay1, bx1, by1);
            compute(1);
        }
    }

    // ---- epilogue: every (j, x) written exactly once ----
    const float scale = 1.0f / 256.0f;
    unsigned base0 = (unsigned)(((b * (GW * GW) + dyi * GW) * Hn + y) * Wn);
    constexpr unsigned PLANE = (unsigned)(Hn * Wn);

#pragma unroll
    for (int a = 0; a < 2; ++a)
#pragma unroll
        for (int n = 0; n < 4; ++n)
#pragma unroll
            for (int r = 0; r < 4; ++r) {
                int xp = (2 * h + a) * 16 + g * 4 + r;   // x'  (C/D row, m89-verified)
                int up = n * 16 + m16;                   // u'  (C/D col)
                int j  = up - xp + 10;
                if ((unsigned)j < 21u)
                    out[base0 + (unsigned)j * PLANE + (unsigned)(2 * xp + p)] = acc[a][n][r] * scale;
            }

    // left edge zeros (u' < 0): j < 10, x' < 10-j — h==0 waves (both parities)
    if (h == 0) {
#pragma unroll
        for (int jj = 0; jj < 10; ++jj)
            if (l < 10 - jj)
                out[base0 + (unsigned)jj * PLANE + (unsigned)(2 * l + p)] = 0.0f;
    } else {
        // right edge zeros (u' >= 64): j > 10, x' >= 74-j — h==1 waves
#pragma unroll
        for (int jj = 11; jj < 21; ++jj)
            if (l < jj - 10)
                out[base0 + (unsigned)jj * PLANE + (unsigned)(2 * (74 - jj + l) + p)] = 0.0f;
    }
}

extern "C" void kernel_launch(void* const* d_in, const int* in_sizes, int n_in,
                              void* d_out, int out_size, void* d_ws, size_t ws_size,
                              hipStream_t stream) {
    const float* in1 = (const float*)d_in[0];
    const float* in2 = (const float*)d_in[1];
    float* out = (float*)d_out;
    corr_mfma<<<NWG, 256, 0, stream>>>(in1, in2, out);
}

// Round 18
// 292.542 us; speedup vs baseline: 1.2166x; 1.2166x over previous
//
#include <hip/hip_runtime.h>
#include <hip/hip_bf16.h>

// FlowNetC correlation via bf16 MFMA Gram (16 tiles/parity).
// out[b, dyi*21+j, y, x] = (1/256) * sum_c in1[b,c,y,x] * in2[b,c,y2,x+2j-20], y2=y+2dyi-20.
// Parity split: x=2x'+p, u=2u'+p, u'=x'+j-10. Per (b,y,dyi,p):
//   G_p[x'][u'] = sum_c A_p[x'][c]*B_p[u'][c]  (64x64, K=256); j=u'-x'+10 in [0,21).
// Round-16 fix: LDS-transposed epilogue. Old epilogue's band stores had lane-varying j
// -> 64 lanes hit 16 j-planes 49KB apart (~64 sectors/store instr, ~200us TA serial-
// ization) -- invariant across r9/r12/r15 barrier variants, which is how it was found.
// New: scatter acc -> padded LDS tile [x][23], then coalesced 21x128 dword stores.

typedef __attribute__((ext_vector_type(8))) short bf16x8;
typedef __attribute__((ext_vector_type(4))) float f32x4;
typedef __attribute__((ext_vector_type(4))) unsigned u32x4;

constexpr int Bn = 8, Cn = 256, Hn = 96, Wn = 128, GW = 21;
constexpr int KC = 32, NCH = Cn / KC;     // 8 chunks of 32 channels
constexpr int NWG = Bn * Hn * GW;         // 16128, divisible by 8
constexpr int CPX = NWG / 8;
constexpr int JW = 23;                    // sout pad: scatter ~2-way, transpose-read free

__device__ inline unsigned pack_bf16(float lo, float hi) {
    __hip_bfloat16 l = __float2bfloat16(lo);
    __hip_bfloat16 h = __float2bfloat16(hi);
    unsigned short lu, hu;
    __builtin_memcpy(&lu, &l, 2);
    __builtin_memcpy(&hu, &h, 2);
    return (unsigned)lu | ((unsigned)hu << 16);
}

// LDS-visibility barrier WITHOUT the vmcnt(0) drain of __syncthreads() (rule #18).
__device__ inline void lds_barrier() {
    asm volatile("s_waitcnt lgkmcnt(0)" ::: "memory");
    __builtin_amdgcn_s_barrier();
    __builtin_amdgcn_sched_barrier(0);
}

__global__ __launch_bounds__(256) void corr_mfma(
    const float* __restrict__ in1, const float* __restrict__ in2,
    float* __restrict__ out)
{
    // [dbuf][panel: Ae,Ao,Be,Bo][1024 uints]; panel = [mt4][kg4][pos16][ku4] of bf16x2
    // Epilogue overlays sout[128][JW] floats (2944 <= 8192 dwords).
    __shared__ unsigned lds[2][4][1024];

    int orig = blockIdx.x;
    int wg  = (orig & 7) * CPX + (orig >> 3);   // bijective XCD chunking
    int dyi = wg % GW;
    int y   = (wg / GW) % Hn;
    int b   = wg / (GW * Hn);
    int y2  = y + 2 * dyi - 20;
    bool y2ok = (y2 >= 0) && (y2 < Hn);

    int tid = threadIdx.x;
    int w   = tid >> 6;          // wave 0..3
    int l   = tid & 63;
    int p   = w >> 1;            // parity
    int h   = w & 1;             // x-half: mt in {2h, 2h+1}
    int g   = l >> 4;            // k-group
    int m16 = l & 15;

    const size_t chw = (size_t)Hn * Wn;
    const float* pA = in1 + ((size_t)b * Cn) * chw + (size_t)y * Wn;
    const float* pB = in2 + ((size_t)b * Cn) * chw + (size_t)(y2ok ? y2 : 0) * Wn;

    // staging task: thread = (tm = x-pair 0..63, tg = kg 0..3); owns channels 8tg..8tg+7
    int tm = tid & 63;
    int tg = tid >> 6;
    const int loff = ((tm >> 4) * 4 + tg) * 64 + (tm & 15) * 4;   // b128-aligned

    f32x4 acc[2][4] = {};        // acc[a][n] = tile (mt=2h+a, nt=n)

    // raw load values as scalar floats (two prefetch sets)
    float ax0[8], ay0[8], bx0[8], by0[8];
    float ax1[8], ay1[8], bx1[8], by1[8];

    auto prefetch = [&](int chunk, float (&ax)[8], float (&ay)[8],
                        float (&bx)[8], float (&by)[8]) {
        size_t base = (size_t)(chunk * KC + 8 * tg) * chw + 2 * tm;
#pragma unroll
        for (int k = 0; k < 8; ++k) {
            float2 tA = *(const float2*)(pA + base + (size_t)k * chw);
            float2 tB = *(const float2*)(pB + base + (size_t)k * chw);
            ax[k] = tA.x; ay[k] = tA.y;
            bx[k] = tB.x; by[k] = tB.y;
        }
        __builtin_amdgcn_sched_barrier(0);   // pin issue point: loads go out here
    };

    auto writeout = [&](int buf, float (&ax)[8], float (&ay)[8],
                        float (&bx)[8], float (&by)[8]) {
#pragma unroll
        for (int k = 0; k < 8; ++k)
            asm volatile("" : "+v"(ax[k]), "+v"(ay[k]), "+v"(bx[k]), "+v"(by[k]));
        u32x4 ae, ao, be, bo;
#pragma unroll
        for (int ku = 0; ku < 4; ++ku) {
            ae[ku] = pack_bf16(ax[2 * ku], ax[2 * ku + 1]);
            ao[ku] = pack_bf16(ay[2 * ku], ay[2 * ku + 1]);
            be[ku] = pack_bf16(bx[2 * ku], bx[2 * ku + 1]);
            bo[ku] = pack_bf16(by[2 * ku], by[2 * ku + 1]);
        }
        *(u32x4*)&lds[buf][0][loff] = ae;
        *(u32x4*)&lds[buf][1][loff] = ao;
        *(u32x4*)&lds[buf][2][loff] = be;
        *(u32x4*)&lds[buf][3][loff] = bo;
    };

    auto compute = [&](int buf) {
        const unsigned* Pa = &lds[buf][p][0];
        const unsigned* Pb = &lds[buf][2 + p][0];
        int fo = g * 64 + m16 * 4;
        bf16x8 A0  = *(const bf16x8*)(Pa + (2 * h + 0) * 256 + fo);
        bf16x8 A1  = *(const bf16x8*)(Pa + (2 * h + 1) * 256 + fo);
        bf16x8 Bf0 = *(const bf16x8*)(Pb + 0 * 256 + fo);
        bf16x8 Bf1 = *(const bf16x8*)(Pb + 1 * 256 + fo);
        bf16x8 Bf2 = *(const bf16x8*)(Pb + 2 * 256 + fo);
        bf16x8 Bf3 = *(const bf16x8*)(Pb + 3 * 256 + fo);
        acc[0][0] = __builtin_amdgcn_mfma_f32_16x16x32_bf16(A0, Bf0, acc[0][0], 0, 0, 0);
        acc[0][1] = __builtin_amdgcn_mfma_f32_16x16x32_bf16(A0, Bf1, acc[0][1], 0, 0, 0);
        acc[0][2] = __builtin_amdgcn_mfma_f32_16x16x32_bf16(A0, Bf2, acc[0][2], 0, 0, 0);
        acc[0][3] = __builtin_amdgcn_mfma_f32_16x16x32_bf16(A0, Bf3, acc[0][3], 0, 0, 0);
        acc[1][0] = __builtin_amdgcn_mfma_f32_16x16x32_bf16(A1, Bf0, acc[1][0], 0, 0, 0);
        acc[1][1] = __builtin_amdgcn_mfma_f32_16x16x32_bf16(A1, Bf1, acc[1][1], 0, 0, 0);
        acc[1][2] = __builtin_amdgcn_mfma_f32_16x16x32_bf16(A1, Bf2, acc[1][2], 0, 0, 0);
        acc[1][3] = __builtin_amdgcn_mfma_f32_16x16x32_bf16(A1, Bf3, acc[1][3], 0, 0, 0);
    };

    if (y2ok) {
        prefetch(0, ax0, ay0, bx0, by0);
        prefetch(1, ax1, ay1, bx1, by1);
        for (int it = 0; it < NCH; it += 2) {
            writeout(0, ax0, ay0, bx0, by0);
            lds_barrier();
            if (it + 2 < NCH) prefetch(it + 2, ax0, ay0, bx0, by0);
            compute(0);
            writeout(1, ax1, ay1, bx1, by1);
            lds_barrier();
            if (it + 3 < NCH) prefetch(it + 3, ax1, ay1, bx1, by1);
            compute(1);
        }
    }

    // ---- epilogue: LDS-transposed, coalesced stores ----
    __syncthreads();                       // all compute/LDS reads done; reuse LDS
    float* sout = (float*)&lds[0][0][0];   // sout[x][JW], x in [0,128), j in [0,21)

    for (int i = tid; i < Wn * JW; i += 256) sout[i] = 0.0f;
    __syncthreads();                       // zeros visible

    if (y2ok) {
        const float scale = 1.0f / 256.0f;
#pragma unroll
        for (int a = 0; a < 2; ++a)
#pragma unroll
            for (int n = 0; n < 4; ++n)
#pragma unroll
                for (int r = 0; r < 4; ++r) {
                    int xp = (2 * h + a) * 16 + g * 4 + r;   // x' (C/D row)
                    int up = n * 16 + m16;                   // u' (C/D col)
                    int j  = up - xp + 10;
                    if ((unsigned)j < 21u)
                        sout[(2 * xp + p) * JW + j] = acc[a][n][r] * scale;
                }
    }
    __syncthreads();                       // scatter visible

    unsigned base0 = (unsigned)(((b * (GW * GW) + dyi * GW) * Hn + y) * Wn);
    constexpr unsigned PLANE = (unsigned)(Hn * Wn);
    for (int s = tid; s < GW * Wn; s += 256) {
        int j = s >> 7;                    // s / 128
        int x = s & 127;
        out[base0 + (unsigned)j * PLANE + (unsigned)x] = sout[x * JW + j];
    }
}

extern "C" void kernel_launch(void* const* d_in, const int* in_sizes, int n_in,
                              void* d_out, int out_size, void* d_ws, size_t ws_size,
                              hipStream_t stream) {
    const float* in1 = (const float*)d_in[0];
    const float* in2 = (const float*)d_in[1];
    float* out = (float*)d_out;
    corr_mfma<<<NWG, 256, 0, stream>>>(in1, in2, out);
}